// Round 2
// baseline (317.862 us; speedup 1.0000x reference)
//
#include <hip/hip_runtime.h>
#include <cstdint>
#include <cstddef>

#define M_TOT 32768   // B*N
#define D_    256
#define DN_   128
#define TWO_D 512
#define H_    1024
#define TWO_H 2048

typedef unsigned short ushort_t;
typedef __attribute__((ext_vector_type(8))) short bf16x8;  // 8 bf16 = 4 VGPRs
typedef __attribute__((ext_vector_type(4))) float f32x4;

__device__ __forceinline__ ushort_t f2bf(float f) {
  union { float f; uint32_t i; } v; v.f = f;
  uint32_t r = v.i + 0x7fffu + ((v.i >> 16) & 1u);
  return (ushort_t)(r >> 16);
}

__device__ __forceinline__ void async_ld16(const void* g, void* l) {
  __builtin_amdgcn_global_load_lds(
      (const __attribute__((address_space(1))) void*)g,
      (__attribute__((address_space(3))) void*)l, 16, 0, 0);
}

// ---------------- tiny cond GEMM: ss[b][j] = ctx[b]·cond_w[:,j] + cond_b[j]  (all f32)
__global__ __launch_bounds__(256) void cond_ss_kernel(
    const float* __restrict__ ctx, const float* __restrict__ cond_w,
    const float* __restrict__ cond_b, float* __restrict__ ss) {
  int j = blockIdx.x * 256 + threadIdx.x;   // 4096 total: b=j>>9, col=j&511
  int b = j >> 9, col = j & 511;
  float acc = cond_b[col];
  for (int k = 0; k < DN_; ++k)
    acc += ctx[b * DN_ + k] * cond_w[k * TWO_D + col];
  ss[j] = acc;
}

// ---------------- prep: f32 weights -> bf16 transposed operand buffers (+emb gather)
__global__ __launch_bounds__(256) void prep_kernel(
    const float* __restrict__ w_in,   // [256][2048] f32
    const float* __restrict__ w_out,  // [1024][256] f32
    const float* __restrict__ emb,    // [1024][2048] f32
    const int* __restrict__ idx,      // [128] (int32, with int64 sniff)
    ushort_t* __restrict__ WinT,      // [2048][256] bf16
    ushort_t* __restrict__ WoutT,     // [256][1024] bf16
    ushort_t* __restrict__ W2T) {     // [1024][256] bf16
  int id = blockIdx.x * 256 + threadIdx.x;   // 1048576 total
  if (id < 524288) {
    int n = id >> 8, k = id & 255;
    WinT[id] = f2bf(w_in[k * TWO_H + n]);
  } else if (id < 786432) {
    int t = id - 524288;
    int n = t >> 10, k = t & 1023;
    WoutT[t] = f2bf(w_out[k * D_ + n]);
  } else {
    int t = id - 786432;
    int c = t >> 8, d = t & 255;           // c = f*8+o
    int f = c >> 3, o = c & 7;
    // int64-vs-int32 sniff: if idx is int64 (<1024 values), odd words are 0
    bool looks64 = (idx[1] == 0) & (idx[3] == 0) & (idx[5] == 0) & (idx[7] == 0);
    int fi = looks64 ? idx[2 * f] : idx[f];
    W2T[t] = f2bf(emb[(size_t)fi * 2048 + d * 8 + o]);
  }
}

// ---------------- fused LayerNorm + FiLM  (one wave per row of 256), f32 in -> bf16 out
__global__ __launch_bounds__(256) void ln_film_kernel(
    const float* __restrict__ x, const float* __restrict__ ss,
    ushort_t* __restrict__ h) {
  int row = blockIdx.x * 4 + (threadIdx.x >> 6);
  int lane = threadIdx.x & 63;
  int b = row >> 12;
  const float* xr = x + (size_t)row * D_;
  float4 pk = *(const float4*)(xr + lane * 4);
  float f0 = pk.x, f1 = pk.y, f2 = pk.z, f3 = pk.w;
  float s = f0 + f1 + f2 + f3;
  float q = f0 * f0 + f1 * f1 + f2 * f2 + f3 * f3;
#pragma unroll
  for (int off = 32; off > 0; off >>= 1) {
    s += __shfl_xor(s, off, 64);
    q += __shfl_xor(q, off, 64);
  }
  float mean = s * (1.0f / 256.0f);
  float var = q * (1.0f / 256.0f) - mean * mean;
  float rs = rsqrtf(var + 1e-5f);
  int d = lane * 4;
  const float* ssb = ss + b * TWO_D;
  float o0 = (f0 - mean) * rs * (1.0f + ssb[d + 0]) + ssb[256 + d + 0];
  float o1 = (f1 - mean) * rs * (1.0f + ssb[d + 1]) + ssb[256 + d + 1];
  float o2 = (f2 - mean) * rs * (1.0f + ssb[d + 2]) + ssb[256 + d + 2];
  float o3 = (f3 - mean) * rs * (1.0f + ssb[d + 3]) + ssb[256 + d + 3];
  uint2 st;
  st.x = (uint32_t)f2bf(o0) | ((uint32_t)f2bf(o1) << 16);
  st.y = (uint32_t)f2bf(o2) | ((uint32_t)f2bf(o3) << 16);
  *(uint2*)(h + (size_t)row * D_ + lane * 4) = st;
}

// ---------------- generic GEMM: C[M][N] = A[M][K] * BT[N][K]^T (+f32 bias)
// 128x128 tile, BK=32, 4 waves (2x2), each wave 64x64 via 4x4 of 16x16x32 MFMA
// OUT_F32: store f32, else bf16.
template <bool BIAS, bool OUT_F32>
__global__ __launch_bounds__(256, 2) void gemm_bt_kernel(
    const ushort_t* __restrict__ A, const ushort_t* __restrict__ BT,
    const float* __restrict__ bias, void* __restrict__ Cout,
    int M, int N, int K) {
  __shared__ ushort_t As[128 * 32];
  __shared__ ushort_t Bs[128 * 32];
  const int tid = threadIdx.x, lane = tid & 63, wave = tid >> 6;
  const int wm = wave >> 1, wn = wave & 1;
  const int m0 = blockIdx.x * 128, n0 = blockIdx.y * 128;
  const int srow = lane >> 2, sch = (lane & 3) * 8;
  f32x4 acc[4][4] = {};
  for (int k0 = 0; k0 < K; k0 += 32) {
    for (int i = wave; i < 8; i += 4) {
      async_ld16(A + (size_t)(m0 + i * 16 + srow) * K + k0 + sch, &As[i * 512]);
      async_ld16(BT + (size_t)(n0 + i * 16 + srow) * K + k0 + sch, &Bs[i * 512]);
    }
    __syncthreads();
    bf16x8 a[4], b[4];
#pragma unroll
    for (int i = 0; i < 4; ++i)
      a[i] = *(const bf16x8*)&As[(wm * 64 + i * 16 + (lane & 15)) * 32 + (lane >> 4) * 8];
#pragma unroll
    for (int j = 0; j < 4; ++j)
      b[j] = *(const bf16x8*)&Bs[(wn * 64 + j * 16 + (lane & 15)) * 32 + (lane >> 4) * 8];
#pragma unroll
    for (int i = 0; i < 4; ++i)
#pragma unroll
      for (int j = 0; j < 4; ++j)
        acc[i][j] = __builtin_amdgcn_mfma_f32_16x16x32_bf16(a[i], b[j], acc[i][j], 0, 0, 0);
    __syncthreads();
  }
#pragma unroll
  for (int j = 0; j < 4; ++j) {
    int col = n0 + wn * 64 + j * 16 + (lane & 15);
    float bv = BIAS ? bias[col] : 0.0f;
#pragma unroll
    for (int i = 0; i < 4; ++i) {
      int rowb = m0 + wm * 64 + i * 16 + ((lane >> 4) << 2);
#pragma unroll
      for (int r = 0; r < 4; ++r) {
        float val = acc[i][j][r] + bv;
        if (OUT_F32)
          ((float*)Cout)[(size_t)(rowb + r) * N + col] = val;
        else
          ((ushort_t*)Cout)[(size_t)(rowb + r) * N + col] = f2bf(val);
      }
    }
  }
}

// ---------------- gated in-proj GEMM: g = gelu(h@Wu + bu) * (h@Wv + bv), bf16 out
// block: 128 rows x 64 gate-cols; wave (wm,wn): 64 rows x 32 cols of BOTH u and v
__global__ __launch_bounds__(256, 2) void gemm_gated_kernel(
    const ushort_t* __restrict__ A,     // h [32768][256] bf16
    const ushort_t* __restrict__ WinT,  // [2048][256] bf16; rows [0,1024)=u, [1024,2048)=v
    const float* __restrict__ bin,      // [2048] f32
    ushort_t* __restrict__ G) {         // [32768][1024] bf16
  __shared__ ushort_t As[128 * 32];
  __shared__ ushort_t Bus[64 * 32];
  __shared__ ushort_t Bvs[64 * 32];
  const int tid = threadIdx.x, lane = tid & 63, wave = tid >> 6;
  const int wm = wave >> 1, wn = wave & 1;
  const int m0 = blockIdx.x * 128;
  const int j0 = blockIdx.y * 64;
  const int srow = lane >> 2, sch = (lane & 3) * 8;
  const int K = 256;
  f32x4 au[4][2] = {}, av[4][2] = {};
  for (int k0 = 0; k0 < K; k0 += 32) {
    for (int i = wave; i < 8; i += 4)
      async_ld16(A + (size_t)(m0 + i * 16 + srow) * K + k0 + sch, &As[i * 512]);
    {
      int i = wave;  // 0..3 covers the 64-row B tiles
      async_ld16(WinT + (size_t)(j0 + i * 16 + srow) * K + k0 + sch, &Bus[i * 512]);
      async_ld16(WinT + (size_t)(1024 + j0 + i * 16 + srow) * K + k0 + sch, &Bvs[i * 512]);
    }
    __syncthreads();
    bf16x8 a[4], bu[2], bv[2];
#pragma unroll
    for (int i = 0; i < 4; ++i)
      a[i] = *(const bf16x8*)&As[(wm * 64 + i * 16 + (lane & 15)) * 32 + (lane >> 4) * 8];
#pragma unroll
    for (int j = 0; j < 2; ++j) {
      bu[j] = *(const bf16x8*)&Bus[(wn * 32 + j * 16 + (lane & 15)) * 32 + (lane >> 4) * 8];
      bv[j] = *(const bf16x8*)&Bvs[(wn * 32 + j * 16 + (lane & 15)) * 32 + (lane >> 4) * 8];
    }
#pragma unroll
    for (int i = 0; i < 4; ++i)
#pragma unroll
      for (int j = 0; j < 2; ++j) {
        au[i][j] = __builtin_amdgcn_mfma_f32_16x16x32_bf16(a[i], bu[j], au[i][j], 0, 0, 0);
        av[i][j] = __builtin_amdgcn_mfma_f32_16x16x32_bf16(a[i], bv[j], av[i][j], 0, 0, 0);
      }
    __syncthreads();
  }
#pragma unroll
  for (int j = 0; j < 2; ++j) {
    int col = j0 + wn * 32 + j * 16 + (lane & 15);
    float bub = bin[col];
    float bvb = bin[1024 + col];
#pragma unroll
    for (int i = 0; i < 4; ++i) {
      int rowb = m0 + wm * 64 + i * 16 + ((lane >> 4) << 2);
#pragma unroll
      for (int r = 0; r < 4; ++r) {
        float u = au[i][j][r] + bub;
        float v = av[i][j][r] + bvb;
        // tanh-approx gelu (JAX default approximate=True)
        float t = 0.7978845608028654f * (u + 0.044715f * u * u * u);
        float e = __expf(2.0f * t);
        float th = 1.0f - 2.0f / (e + 1.0f);
        float gl = 0.5f * u * (1.0f + th);
        G[(size_t)(rowb + r) * 1024 + col] = f2bf(gl * v);
      }
    }
  }
}

extern "C" void kernel_launch(void* const* d_in, const int* in_sizes, int n_in,
                              void* d_out, int out_size, void* d_ws, size_t ws_size,
                              hipStream_t stream) {
  const float* x      = (const float*)d_in[0];
  const float* ctx    = (const float*)d_in[1];
  const int*   idx    = (const int*)d_in[2];
  const float* cond_w = (const float*)d_in[3];
  const float* cond_b = (const float*)d_in[4];
  const float* w_in   = (const float*)d_in[5];
  const float* b_in   = (const float*)d_in[6];
  const float* w_out  = (const float*)d_in[7];
  const float* b_out  = (const float*)d_in[8];
  const float* emb    = (const float*)d_in[9];

  char* w = (char*)d_ws;
  float* ss = (float*)w;           w += (size_t)8 * TWO_D * 4;        // 16 KB
  ushort_t* h = (ushort_t*)w;      w += (size_t)M_TOT * D_ * 2;       // 16.8 MB
  ushort_t* y = (ushort_t*)w;      w += (size_t)M_TOT * D_ * 2;       // 16.8 MB
  ushort_t* WinT = (ushort_t*)w;   w += (size_t)TWO_H * D_ * 2;       // 1 MB
  ushort_t* WoutT = (ushort_t*)w;  w += (size_t)D_ * H_ * 2;          // 0.5 MB
  ushort_t* W2T = (ushort_t*)w;    w += (size_t)H_ * D_ * 2;          // 0.5 MB
  // g (bf16 [32768][1024], 67 MB) parked in the f32 d_out buffer (134 MB);
  // fully rewritten before any read, overwritten by the final f32 GEMM after G2.
  ushort_t* g = (ushort_t*)d_out;

  cond_ss_kernel<<<16, 256, 0, stream>>>(ctx, cond_w, cond_b, ss);
  prep_kernel<<<4096, 256, 0, stream>>>(w_in, w_out, emb, idx, WinT, WoutT, W2T);
  ln_film_kernel<<<M_TOT / 4, 256, 0, stream>>>(x, ss, h);
  gemm_gated_kernel<<<dim3(256, 16), 256, 0, stream>>>(h, WinT, b_in, g);
  gemm_bt_kernel<true, false><<<dim3(256, 2), 256, 0, stream>>>(g, WoutT, b_out, y, M_TOT, 256, 1024);
  gemm_bt_kernel<false, true><<<dim3(256, 8), 256, 0, stream>>>(y, W2T, nullptr, d_out, M_TOT, 1024, 256);
}